// Round 9
// baseline (10135.018 us; speedup 1.0000x reference)
//
#include <hip/hip_runtime.h>
#include <math.h>

#define NN 512      // nodes
#define NB 256      // batch
#define NT 200      // time steps
#define TPB 128     // 2 waves; block owns 32 cols
#define NTEAM 16    // blocks per team (16 x 32 cols = 512)

typedef unsigned long long u64;
typedef _Float16 half8 __attribute__((ext_vector_type(8)));
typedef float f32x4 __attribute__((ext_vector_type(4)));

// ws layout in floats
#define WS_WM  0                       // Wm = W1*mask  [512*512]
#define WS_H   (NN*NN)                 // h buffer      [256*512]
#define WS_YS  (WS_H + NB*NN)          // y_stage       [256*512]
#define WS_CNT (WS_YS + NB*NN)         // 32 team counters, stride 32 u32

// ---- MALL-coherent ops via compiler-generated scoped atomics (no asm) ----
__device__ __forceinline__ void sysst_u64(u64* p, u64 v) {
  __hip_atomic_store(p, v, __ATOMIC_RELAXED, __HIP_MEMORY_SCOPE_SYSTEM);
}
__device__ __forceinline__ u64 sysld_u64(const u64* p) {
  return __hip_atomic_load(p, __ATOMIC_RELAXED, __HIP_MEMORY_SCOPE_SYSTEM);
}
__device__ __forceinline__ void sysst_f1(float* p, float v) {
  __hip_atomic_store(p, v, __ATOMIC_RELAXED, __HIP_MEMORY_SCOPE_SYSTEM);
}
__device__ __forceinline__ float sysld_f1(const float* p) {
  return __hip_atomic_load(p, __ATOMIC_RELAXED, __HIP_MEMORY_SCOPE_SYSTEM);
}

__global__ __launch_bounds__(256)
void k_init(const float* __restrict__ W1, const float* __restrict__ mask,
            const float* __restrict__ x_init, float* __restrict__ ws,
            float* __restrict__ out) {
  int gt = blockIdx.x * 256 + threadIdx.x;
  int stride = gridDim.x * 256;
  for (int i = gt; i < NN * NN; i += stride) ws[WS_WM + i] = W1[i] * mask[i];
  for (int i = gt; i < NB * NN / 2; i += stride) {
    u64 q = ((const u64*)x_init)[i];
    int r = i >> 8, np = i & 255;
    *((u64*)(out + (size_t)r * NT * NN) + np) = q;   // traj[:,0,:]
    sysst_u64((u64*)(ws + WS_YS) + i, q);            // y_stage at MALL
  }
  if (gt < 32 * 32)
    __hip_atomic_store(((unsigned*)(ws + WS_CNT)) + gt, 0u,
                       __ATOMIC_RELAXED, __HIP_MEMORY_SCOPE_SYSTEM);
}

__device__ __forceinline__ void team_release(unsigned* cnt) {
  __syncthreads();   // each wave drains vmcnt(0) before s_barrier
  if (threadIdx.x == 0) atomicAdd(cnt, 1u);
}
__device__ __forceinline__ void team_wait(unsigned* cnt, unsigned target) {
  if (threadIdx.x == 0) {
    while (__hip_atomic_load(cnt, __ATOMIC_RELAXED,
                             __HIP_MEMORY_SCOPE_AGENT) < target)
      __builtin_amdgcn_s_sleep(1);
  }
  __syncthreads();
}

// Stage 8 rows x 512 fp32 (stride NN) from MALL -> split fp16 planes (swz).
// 128 threads: each does 32 floats (16 u64 loads) -> 4 half8 granules.
__device__ __forceinline__ void stage8(_Float16* __restrict__ pH,
                                       _Float16* __restrict__ pL,
                                       const float* __restrict__ src,
                                       int tid) {
  const int row = tid >> 4;        // 0..7
  const int seg = tid & 15;        // 0..15, 32 floats each
  const u64* s = (const u64*)(src + (size_t)row * NN) + seg * 16;
  u64 tmp[16];
#pragma unroll
  for (int i = 0; i < 16; ++i) tmp[i] = sysld_u64(s + i);
  half8* dH = (half8*)pH;
  half8* dL = (half8*)pL;
#pragma unroll
  for (int q = 0; q < 4; ++q) {
    half8 hv, lv;
#pragma unroll
    for (int e = 0; e < 4; ++e) {
      union { u64 q64; float f[2]; } u; u.q64 = tmp[q * 4 + e];
#pragma unroll
      for (int x = 0; x < 2; ++x) {
        float f = u.f[x]; _Float16 h = (_Float16)f;
        hv[e * 2 + x] = h;
        lv[e * 2 + x] = (_Float16)((f - (float)h) * 2048.0f);
      }
    }
    int g = seg * 4 + q;
    int idx = row * 64 + (g ^ row);          // row<8 so row == row&7
    dH[idx] = hv; dL[idx] = lv;
  }
}

// Full-K GEMM for this wave's 16x16 tile. A rows 8-15 duplicate rows 0-7
// (C rows 8-15 are discarded; M-dim is separable so duplicates are harmless).
__device__ __forceinline__ void gemm_tile(const _Float16* yHb, const _Float16* yLb,
                                          const _Float16* wb,
                                          int rc, int kg, int wv, float res[4]) {
  const int swz = rc & 7;
  const half8* pAH = (const half8*)yHb;
  const half8* pAL = (const half8*)yLb;
  const half8* pB  = (const half8*)wb;
  const int abase = (rc & 7) * 64;
  const int bbase = (wv * 16 + rc) * 64;
  f32x4 aH = {0.f, 0.f, 0.f, 0.f};
  f32x4 aL = {0.f, 0.f, 0.f, 0.f};
#pragma unroll
  for (int kt = 0; kt < 16; ++kt) {
    const int gs = (kt * 4 + kg) ^ swz;
    half8 av = pAH[abase + gs];
    half8 al = pAL[abase + gs];
    half8 bv = pB[bbase + gs];
    aH = __builtin_amdgcn_mfma_f32_16x16x32_f16(av, bv, aH, 0, 0, 0);
    aL = __builtin_amdgcn_mfma_f32_16x16x32_f16(al, bv, aL, 0, 0, 0);
  }
#pragma unroll
  for (int r = 0; r < 4; ++r) res[r] = aH[r] + aL[r] * (1.0f / 2048.0f);
}

__global__ __launch_bounds__(TPB, 1)
void k_ode(const float* __restrict__ tspan,
           const float* __restrict__ W2g,
           const float* __restrict__ b1,
           const float* __restrict__ b2,
           float* __restrict__ ws,
           float* __restrict__ out) {
  extern __shared__ _Float16 ldsh[];
  _Float16* w1 = ldsh;                 // [32 cols][64 granules half8] 32KB
  _Float16* w2 = ldsh + 16384;         // 32KB
  _Float16* yH = ldsh + 32768;         // [8 rows][64 granules] 8KB
  _Float16* yL = ldsh + 36864;         // 8KB   -> total 80KB (2 blocks/CU)

  const int bid = blockIdx.x;
  const int rg = bid & 31, cg = bid >> 5;   // co-resident blocks: diff teams
  const int r0 = rg * 8, j0 = cg * 32;
  const int tid = threadIdx.x;
  const int lane = tid & 63, wv = tid >> 6;  // wv 0..1
  const int rc = lane & 15, kg = lane >> 4;
  const int mycol = j0 + wv * 16 + rc;
  const bool act = (kg < 2);           // rows kg*4..+3 valid (<8)

  const float* Wm = ws + WS_WM;
  float* hbuf = ws + WS_H;
  float* ystg = ws + WS_YS;
  unsigned* cnt = ((unsigned*)(ws + WS_CNT)) + rg * 32;

  // --- prologue: weights -> fp16 single planes (swizzled) ---
  {
    const int col = tid >> 2;          // 0..31
    const int part = tid & 3;          // 0..3, 16 granules each
    const float* s1 = Wm  + (size_t)(j0 + col) * NN + part * 128;
    const float* s2 = W2g + (size_t)(j0 + col) * NN + part * 128;
    half8* d1 = (half8*)w1;
    half8* d2 = (half8*)w2;
    const int key = col & 7;
#pragma unroll
    for (int i = 0; i < 16; ++i) {
      int g = part * 16 + i;
      int idx = col * 64 + (g ^ key);
      half8 hv;
#pragma unroll
      for (int e = 0; e < 8; ++e) hv[e] = (_Float16)s1[i * 8 + e];
      d1[idx] = hv;
#pragma unroll
      for (int e = 0; e < 8; ++e) hv[e] = (_Float16)s2[i * 8 + e];
      d2[idx] = hv;
    }
  }
  const float b1s = b1[mycol], b2s = b2[mycol];
  __syncthreads();

  unsigned epoch = 0;
  float yb[4], ac[4];
  float res[4];

  for (int t = 0; t < NT - 1; ++t) {
    const float dt = tspan[t + 1] - tspan[t];
#pragma unroll 1
    for (int s = 0; s < 4; ++s) {
      // ---------- phase 1: h = tanh(y . W1^T + b1) ----------
      stage8(yH, yL, ystg + (size_t)r0 * NN, tid);
      if (s == 0 && act) {  // latch exact fp32 y_base for this RK4 step
#pragma unroll
        for (int r = 0; r < 4; ++r)
          yb[r] = sysld_f1(ystg + (size_t)(r0 + kg * 4 + r) * NN + mycol);
      }
      __syncthreads();

      gemm_tile(yH, yL, w1, rc, kg, wv, res);
      if (act) {
#pragma unroll
        for (int r = 0; r < 4; ++r)
          sysst_f1(hbuf + (size_t)(r0 + kg * 4 + r) * NN + mycol,
                   tanhf(res[r] + b1s));
      }
      team_release(cnt); ++epoch;
      team_wait(cnt, NTEAM * epoch);

      // ---------- phase 2: k = h . W2^T + b2, RK4 combine ----------
      stage8(yH, yL, hbuf + (size_t)r0 * NN, tid);
      __syncthreads();

      gemm_tile(yH, yL, w2, rc, kg, wv, res);
      if (act) {
#pragma unroll
        for (int r = 0; r < 4; ++r) {
          float k = res[r] + b2s;
          float yn;
          if (s == 0)      { ac[r] = k;          yn = yb[r] + (dt * k) * 0.5f; }
          else if (s == 1) { ac[r] += 2.f * k;   yn = yb[r] + (dt * k) * 0.5f; }
          else if (s == 2) { ac[r] += 2.f * k;   yn = yb[r] + dt * k; }
          else {
            ac[r] += k;
            yn = yb[r] + (dt / 6.0f) * ac[r];
            out[((size_t)(r0 + kg * 4 + r) * NT + (t + 1)) * NN + mycol] = yn;
          }
          sysst_f1(ystg + (size_t)(r0 + kg * 4 + r) * NN + mycol, yn);
        }
      }
      team_release(cnt); ++epoch;
      team_wait(cnt, NTEAM * epoch);
    }
  }
}

extern "C" void kernel_launch(void* const* d_in, const int* in_sizes, int n_in,
                              void* d_out, int out_size, void* d_ws, size_t ws_size,
                              hipStream_t stream) {
  const float* x_init = (const float*)d_in[0];
  const float* tspan  = (const float*)d_in[1];
  const float* W1     = (const float*)d_in[2];
  const float* b1     = (const float*)d_in[3];
  const float* W2     = (const float*)d_in[4];
  const float* b2     = (const float*)d_in[5];
  const float* mask   = (const float*)d_in[6];
  float* out = (float*)d_out;
  float* ws  = (float*)d_ws;

  hipLaunchKernelGGL(k_init, dim3(256), dim3(256), 0, stream,
                     W1, mask, x_init, ws, out);

  const unsigned ldsBytes = 80 * 1024;  // w1 32K + w2 32K + yH 8K + yL 8K
  (void)hipFuncSetAttribute((const void*)k_ode,
                            hipFuncAttributeMaxDynamicSharedMemorySize,
                            (int)ldsBytes);

  // 512 blocks x 80KB LDS = exactly 2 blocks/CU on 256 CUs; all blocks
  // co-resident by capacity, so the team spin-barrier is safe. Co-resident
  // blocks belong to different teams (team = bid&31) -> two independent
  // latency chains per CU hide each other's MALL/barrier latency.
  hipLaunchKernelGGL(k_ode, dim3(512), dim3(TPB), ldsBytes, stream,
                     tspan, W2, b1, b2, ws, out);
}

// Round 10
// 2895.352 us; speedup vs baseline: 3.5004x; 3.5004x over previous
//
#include <hip/hip_runtime.h>
#include <math.h>

#define NN 512      // nodes
#define NB 256      // batch
#define NT 200      // time steps
#define TPB 256
#define NTEAM 8     // blocks per team (64 cols each)

typedef unsigned long long u64;
typedef _Float16 half8 __attribute__((ext_vector_type(8)));
typedef float f32x4 __attribute__((ext_vector_type(4)));

// ws layout (float offsets)
#define WS_WM  0                        // Wm = W1*mask fp32 [512*512]
#define WS_WC  (NN*NN)                  // Wc = Wm*W2  fp16 [512*512] (halves)
#define WS_C   (WS_WC + NN*NN/2)        // c = b2*Wm^T fp32 [512]
#define WS_H   (WS_C + NN)              // hbuf (overlaid x0) fp32 [256*512]
#define WS_CNT (WS_H + NB*NN)           // flags: 32 teams x 8 blocks x 16 u32

// ---- MALL-coherent ops via compiler-generated scoped atomics (no asm) ----
__device__ __forceinline__ void sysst_u64(u64* p, u64 v) {
  __hip_atomic_store(p, v, __ATOMIC_RELAXED, __HIP_MEMORY_SCOPE_SYSTEM);
}
__device__ __forceinline__ u64 sysld_u64(const u64* p) {
  return __hip_atomic_load(p, __ATOMIC_RELAXED, __HIP_MEMORY_SCOPE_SYSTEM);
}
__device__ __forceinline__ void sysst_f1(float* p, float v) {
  __hip_atomic_store(p, v, __ATOMIC_RELAXED, __HIP_MEMORY_SCOPE_SYSTEM);
}
__device__ __forceinline__ float sysld_f1(const float* p) {
  return __hip_atomic_load(p, __ATOMIC_RELAXED, __HIP_MEMORY_SCOPE_SYSTEM);
}

__global__ __launch_bounds__(256)
void k_init(const float* __restrict__ W1, const float* __restrict__ mask,
            const float* __restrict__ x_init, float* __restrict__ ws,
            float* __restrict__ out) {
  int gt = blockIdx.x * 256 + threadIdx.x;
  int stride = gridDim.x * 256;
  for (int i = gt; i < NN * NN; i += stride) ws[WS_WM + i] = W1[i] * mask[i];
  for (int i = gt; i < NB * NN / 2; i += stride) {
    u64 q = ((const u64*)x_init)[i];
    int r = i >> 8, np = i & 255;
    *((u64*)(out + (size_t)r * NT * NN) + np) = q;   // traj[:,0,:]
  }
  if (gt < 32 * NTEAM * 16)
    __hip_atomic_store(((unsigned*)(ws + WS_CNT)) + gt, 0u,
                       __ATOMIC_RELAXED, __HIP_MEMORY_SCOPE_SYSTEM);
}

// One block per node j: Wc[j][:] (fp16), c[j], and x0[:,j] = y0 . Wm[j,:].
// Exploits Wm row sparsity (~10% nonzero) with a wave-uniform skip.
__global__ __launch_bounds__(128)
void k_prep(const float* __restrict__ W2g, const float* __restrict__ b2,
            const float* __restrict__ x_init, float* __restrict__ ws) {
  __shared__ float w1row[NN];
  const int j = blockIdx.x;
  const int t = threadIdx.x;
  const float* wm = ws + WS_WM + (size_t)j * NN;
  for (int i = t; i < NN; i += 128) w1row[i] = wm[i];
  __syncthreads();

  // Wc[j][4t..4t+3] = sum_m w1row[m] * W2[m][4t..4t+3]
  f32x4 acc = {0.f, 0.f, 0.f, 0.f};
  for (int m = 0; m < NN; ++m) {
    float w = w1row[m];
    if (w != 0.f)
      acc += w * ((const f32x4*)(W2g + (size_t)m * NN))[t];
  }
  _Float16* wcrow = (_Float16*)(ws + WS_WC) + (size_t)j * NN;
#pragma unroll
  for (int e = 0; e < 4; ++e) wcrow[4 * t + e] = (_Float16)acc[e];

  if (t == 0) {   // c[j] = sum_m b2[m] * Wm[j][m]
    float s = 0.f;
    for (int m = 0; m < NN; ++m)
      if (w1row[m] != 0.f) s += b2[m] * w1row[m];
    ws[WS_C + j] = s;
  }

  // x0[r][j] = sum_m y0[r][m] * Wm[j][m]  (sys store into hbuf overlay)
#pragma unroll
  for (int rr = 0; rr < 2; ++rr) {
    int r = t + rr * 128;
    const float* y0 = x_init + (size_t)r * NN;
    float s = 0.f;
    for (int m = 0; m < NN; ++m) {
      float w = w1row[m];
      if (w != 0.f) s = fmaf(y0[m], w, s);
    }
    sysst_f1(ws + WS_H + (size_t)r * NN + j, s);
  }
}

// Flag barrier: per-block flag on its own 64B line (no RMW serialization).
__device__ __forceinline__ void team_release(unsigned* flags, int cg, unsigned e) {
  __syncthreads();   // each wave drains vmcnt(0) before s_barrier -> h visible
  if (threadIdx.x == 0)
    __hip_atomic_store(flags + cg * 16, e, __ATOMIC_RELAXED,
                       __HIP_MEMORY_SCOPE_SYSTEM);
}
__device__ __forceinline__ void team_wait(unsigned* flags, unsigned e) {
  if (threadIdx.x < NTEAM) {
    while (__hip_atomic_load(flags + threadIdx.x * 16, __ATOMIC_RELAXED,
                             __HIP_MEMORY_SCOPE_AGENT) < e)
      __builtin_amdgcn_s_sleep(1);
  }
  __syncthreads();
}

// Stage 8 rows x 512 fp32 (stride NN) from MALL -> split fp16 planes (swz).
__device__ __forceinline__ void stage8(_Float16* __restrict__ pH,
                                       _Float16* __restrict__ pL,
                                       const float* __restrict__ src,
                                       int tid) {
  const int row = tid >> 5;        // 0..7
  const int segq = tid & 31;       // 0..31, 16 floats each
  const u64* s = (const u64*)(src + (size_t)row * NN) + segq * 8;
  u64 tmp[8];
#pragma unroll
  for (int i = 0; i < 8; ++i) tmp[i] = sysld_u64(s + i);
  half8* dH = (half8*)pH;
  half8* dL = (half8*)pL;
#pragma unroll
  for (int q = 0; q < 2; ++q) {
    half8 hv, lv;
#pragma unroll
    for (int e = 0; e < 4; ++e) {
      union { u64 q64; float f[2]; } u; u.q64 = tmp[q * 4 + e];
#pragma unroll
      for (int x = 0; x < 2; ++x) {
        float f = u.f[x]; _Float16 h = (_Float16)f;
        hv[e * 2 + x] = h;
        lv[e * 2 + x] = (_Float16)((f - (float)h) * 2048.0f);
      }
    }
    int g = segq * 2 + q;
    int idx = row * 64 + (g ^ row);
    dH[idx] = hv; dL[idx] = lv;
  }
}

// Full-K GEMM for this wave's 16x16 tile. A rows 8-15 duplicate rows 0-7.
__device__ __forceinline__ void gemm_tile(const _Float16* yHb, const _Float16* yLb,
                                          const _Float16* wb,
                                          int rc, int kg, int wv, float res[4]) {
  const int swz = rc & 7;
  const half8* pAH = (const half8*)yHb;
  const half8* pAL = (const half8*)yLb;
  const half8* pB  = (const half8*)wb;
  const int abase = (rc & 7) * 64;
  const int bbase = (wv * 16 + rc) * 64;
  f32x4 aH = {0.f, 0.f, 0.f, 0.f};
  f32x4 aL = {0.f, 0.f, 0.f, 0.f};
#pragma unroll
  for (int kt = 0; kt < 16; ++kt) {
    const int gs = (kt * 4 + kg) ^ swz;
    half8 av = pAH[abase + gs];
    half8 al = pAL[abase + gs];
    half8 bv = pB[bbase + gs];
    aH = __builtin_amdgcn_mfma_f32_16x16x32_f16(av, bv, aH, 0, 0, 0);
    aL = __builtin_amdgcn_mfma_f32_16x16x32_f16(al, bv, aL, 0, 0, 0);
  }
#pragma unroll
  for (int r = 0; r < 4; ++r) res[r] = aH[r] + aL[r] * (1.0f / 2048.0f);
}

__global__ __launch_bounds__(TPB, 1)
void k_ode(const float* __restrict__ tspan,
           const float* __restrict__ W2g,
           const float* __restrict__ b1,
           const float* __restrict__ b2,
           float* __restrict__ ws,
           float* __restrict__ out,
           const float* __restrict__ x_init) {
  extern __shared__ _Float16 ldsh[];
  _Float16* wc = ldsh;                 // [64 cols][64 granules] 64KB
  _Float16* w2 = ldsh + 32768;         // 64KB
  _Float16* hH = ldsh + 65536;         // [8 rows][64 granules] 16KB
  _Float16* hL = ldsh + 73728;         // 16KB  -> 160KB total

  const int bid = blockIdx.x;
  const int cg = bid & 7, rg = bid >> 3;
  const int r0 = rg * 8, j0 = cg * 64;
  const int tid = threadIdx.x;
  const int lane = tid & 63, wv = tid >> 6;
  const int rc = lane & 15, kg = lane >> 4;
  const int mycol = j0 + wv * 16 + rc;
  const bool act = (kg < 2);           // rows kg*4..+3 valid (<8)

  float* hbuf = ws + WS_H;
  unsigned* flags = ((unsigned*)(ws + WS_CNT)) + rg * (NTEAM * 16);

  // --- prologue: Wc (fp16 in ws) and W2 (fp32 global) -> LDS planes ---
  {
    const int col = tid >> 2;          // 0..63
    const int part = tid & 3;          // 0..3, 16 granules each
    const half8* s1 = (const half8*)((const _Float16*)(ws + WS_WC)
                                     + (size_t)(j0 + col) * NN) + part * 16;
    const float* s2 = W2g + (size_t)(j0 + col) * NN + part * 128;
    half8* d1 = (half8*)wc;
    half8* d2 = (half8*)w2;
    const int key = col & 7;
#pragma unroll
    for (int i = 0; i < 16; ++i) {
      int g = part * 16 + i;
      int idx = col * 64 + (g ^ key);
      d1[idx] = s1[i];
      half8 hv;
#pragma unroll
      for (int e = 0; e < 8; ++e) hv[e] = (_Float16)s2[i * 8 + e];
      d2[idx] = hv;
    }
  }
  const float b1s = b1[mycol], b2s = b2[mycol];
  const float c_own = ws[WS_C + mycol];

  // latch register state: xb (from k_prep via hbuf overlay), yb (= x_init)
  float xb[4], yb[4];
  if (act) {
#pragma unroll
    for (int r = 0; r < 4; ++r) {
      xb[r] = sysld_f1(hbuf + (size_t)(r0 + kg * 4 + r) * NN + mycol);
      yb[r] = x_init[(size_t)(r0 + kg * 4 + r) * NN + mycol];
    }
  }
  __syncthreads();

  unsigned epoch = 0;
  float res[4], res2[4];

  for (int t = 0; t < NT - 1; ++t) {
    const float dt = tspan[t + 1] - tspan[t];
    const float alf[3] = {dt * 0.5f, dt * 0.5f, dt};
    float xs[4], H[4];
    if (act) {
#pragma unroll
      for (int r = 0; r < 4; ++r) xs[r] = xb[r];
    }
    // ---- stages 1..3: exchange h_s, x_{s+1} = xb + a*(h_s.Wc^T + c) ----
#pragma unroll
    for (int s = 0; s < 3; ++s) {
      if (act) {
#pragma unroll
        for (int r = 0; r < 4; ++r) {
          float h = tanhf(xs[r] + b1s);
          H[r] = (s == 0) ? h : fmaf(2.f, h, H[r]);
          sysst_f1(hbuf + (size_t)(r0 + kg * 4 + r) * NN + mycol, h);
        }
      }
      team_release(flags, cg, ++epoch);
      team_wait(flags, epoch);
      stage8(hH, hL, hbuf + (size_t)r0 * NN, tid);
      __syncthreads();
      gemm_tile(hH, hL, wc, rc, kg, wv, res);
      if (act) {
#pragma unroll
        for (int r = 0; r < 4; ++r)
          xs[r] = xb[r] + alf[s] * (res[r] + c_own);
      }
    }
    // ---- stage 4: H finalize, exchange H, two GEMMs, step update ----
    if (act) {
#pragma unroll
      for (int r = 0; r < 4; ++r) {
        H[r] += tanhf(xs[r] + b1s);
        sysst_f1(hbuf + (size_t)(r0 + kg * 4 + r) * NN + mycol, H[r]);
      }
    }
    team_release(flags, cg, ++epoch);
    team_wait(flags, epoch);
    stage8(hH, hL, hbuf + (size_t)r0 * NN, tid);
    __syncthreads();
    gemm_tile(hH, hL, wc, rc, kg, wv, res);
    gemm_tile(hH, hL, w2, rc, kg, wv, res2);
    if (act) {
      const float c6 = dt / 6.0f;
#pragma unroll
      for (int r = 0; r < 4; ++r) {
        xb[r] += c6 * res[r] + dt * c_own;
        yb[r] += c6 * res2[r] + dt * b2s;
        out[((size_t)(r0 + kg * 4 + r) * NT + (t + 1)) * NN + mycol] = yb[r];
      }
    }
  }
}

extern "C" void kernel_launch(void* const* d_in, const int* in_sizes, int n_in,
                              void* d_out, int out_size, void* d_ws, size_t ws_size,
                              hipStream_t stream) {
  const float* x_init = (const float*)d_in[0];
  const float* tspan  = (const float*)d_in[1];
  const float* W1     = (const float*)d_in[2];
  const float* b1     = (const float*)d_in[3];
  const float* W2     = (const float*)d_in[4];
  const float* b2     = (const float*)d_in[5];
  const float* mask   = (const float*)d_in[6];
  float* out = (float*)d_out;
  float* ws  = (float*)d_ws;

  hipLaunchKernelGGL(k_init, dim3(256), dim3(256), 0, stream,
                     W1, mask, x_init, ws, out);
  hipLaunchKernelGGL(k_prep, dim3(512), dim3(128), 0, stream,
                     W2, b2, x_init, ws);

  const unsigned ldsBytes = 160 * 1024;  // wc 64K + w2 64K + hH 16K + hL 16K
  (void)hipFuncSetAttribute((const void*)k_ode,
                            hipFuncAttributeMaxDynamicSharedMemorySize,
                            (int)ldsBytes);

  // 256 blocks x 160KB LDS = 1 block/CU on 256 CUs; all co-resident, spin
  // barrier safe (proven rounds 6-8). 4 flag-barriers per RK4 step.
  hipLaunchKernelGGL(k_ode, dim3(256), dim3(TPB), ldsBytes, stream,
                     tspan, W2, b1, b2, ws, out, x_init);
}